// Round 6
// baseline (504.158 us; speedup 1.0000x reference)
//
#include <hip/hip_runtime.h>
#include <hip/hip_bf16.h>
#include <stdint.h>

#define NN 8192
#define DIN 512
#define DOUT 256
#define NSPLIT 8
#define STRIP (NN / NSPLIT) /* 1024 */
#define NSTEP (STRIP / 32)  /* 32 */
#define LOG2E 1.4426950408889634f

typedef short short8 __attribute__((ext_vector_type(8)));
typedef float floatx4 __attribute__((ext_vector_type(4)));

__device__ __forceinline__ unsigned short f2bf_rne(float x) {
  unsigned u = __float_as_uint(x);
  u += 0x7fffu + ((u >> 16) & 1u);
  return (unsigned short)(u >> 16);
}

// packed RNE f32->bf16 pair: low16 = bf16(lo), high16 = bf16(hi)
__device__ __forceinline__ unsigned cvt_pk_bf16(float lo, float hi) {
  unsigned r;
  asm("v_cvt_pk_bf16_f32 %0, %1, %2" : "=v"(r) : "v"(lo), "v"(hi));
  return r;
}

// -------- weight transpose+cvt: W fp32 [512][256] -> WT bf16 [256][512] --------
__global__ __launch_bounds__(256) void kt_transpose(const float* __restrict__ Wg,
                                                    unsigned short* __restrict__ WT) {
  __shared__ unsigned short sm[32][33];
  int tid = threadIdx.x;
  int bk = blockIdx.x >> 3;  // k tile
  int bn = blockIdx.x & 7;   // n tile
  int k0 = bk * 32, n0 = bn * 32;
  int r = tid >> 3, c4 = (tid & 7) * 4;
  const float* src = Wg + (size_t)(k0 + r) * DOUT + n0 + c4;
#pragma unroll
  for (int x = 0; x < 4; ++x) sm[r][c4 + x] = f2bf_rne(src[x]);
  __syncthreads();
  unsigned short* dst = WT + (size_t)(n0 + r) * DIN + k0 + c4;
#pragma unroll
  for (int x = 0; x < 4; ++x) dst[x] = sm[c4 + x][r];
}

// -------- X fp32 [8192][512] -> Xb bf16 (aliases accg workspace; accg memset
//          happens AFTER gemm1 consumes Xb) --------
__global__ __launch_bounds__(256) void kt_cvtx(const float* __restrict__ X,
                                               unsigned short* __restrict__ Xb) {
  int g = blockIdx.x * 256 + threadIdx.x;  // one 8-float group per thread
  const float4* p = (const float4*)(X + (size_t)g * 8);
  float4 a = p[0], b = p[1];
  union { unsigned u[4]; short8 s8; } r;
  r.u[0] = cvt_pk_bf16(a.x, a.y);
  r.u[1] = cvt_pk_bf16(a.z, a.w);
  r.u[2] = cvt_pk_bf16(b.x, b.y);
  r.u[3] = cvt_pk_bf16(b.z, b.w);
  *(short8*)(Xb + (size_t)g * 8) = r.s8;
}

// -- GEMM1 (R5-proven LDS-staged structure). ONLY change vs R5: WhT is written
//    in STEP-BLOCKED layout WhT[j>>5][d][j&31] so attn's per-step 16KB tile is
//    contiguous in memory (fully coalesced staging; the R5 [d][i] layout made
//    every staging b128 touch 64 distinct cache lines — the measured stall). --
__global__ __launch_bounds__(256, 2) void kt_gemm1(const unsigned short* __restrict__ Xb,
                                                   const unsigned short* __restrict__ WT,
                                                   const float* __restrict__ Ab,
                                                   unsigned short* __restrict__ WhTb,
                                                   float* __restrict__ Wh1,
                                                   float* __restrict__ Wh2) {
  __shared__ __align__(16) unsigned short xs[64 * DIN];  // 64 KB
  int tid = threadIdx.x;
  int w = tid >> 6, lane = tid & 63;
  int col = lane & 15, q = lane >> 4;
  int ib = blockIdx.x & 127;  // i block (64 each)
  int db = blockIdx.x >> 7;   // d block (64 each)
  int i0 = ib * 64;

  // ---- stage X tile: thread owns row sr = tid>>2, chunks l = (tid&3) + 4n ----
  int sr = tid >> 2, sc = tid & 3, sxor = sr & 7;
  const unsigned short* gX = Xb + (size_t)(i0 + sr) * DIN + sc * 8;
  unsigned short* lX = xs + sr * DIN;
  short8 stg[8];
#pragma unroll
  for (int n = 0; n < 8; ++n) stg[n] = *(const short8*)(gX + n * 32);
#pragma unroll
  for (int n = 0; n < 8; ++n) {
    int l = sc + n * 4;
    *(short8*)(lX + ((l ^ sxor) * 8)) = stg[n];
  }
#pragma unroll
  for (int n = 8; n < 16; ++n) stg[n - 8] = *(const short8*)(gX + n * 32);
#pragma unroll
  for (int n = 8; n < 16; ++n) {
    int l = sc + n * 4;
    *(short8*)(lX + ((l ^ sxor) * 8)) = stg[n - 8];
  }

  // ---- prefetch all 16 A-frags (fly during the barrier drain) ----
  int drow = db * 64 + w * 16 + col;  // A row (d)
  const unsigned short* abase = WT + (size_t)drow * DIN + q * 8;
  short8 af[16];
#pragma unroll
  for (int s = 0; s < 16; ++s) af[s] = *(const short8*)(abase + s * 32);

  __syncthreads();

  floatx4 acc[4];
#pragma unroll
  for (int t = 0; t < 4; ++t) acc[t] = (floatx4)(0.0f);
  int cx = col & 7;  // reader XOR: (t*16+col)&7 == col&7
#pragma unroll
  for (int s = 0; s < 16; ++s) {
#pragma unroll
    for (int t = 0; t < 4; ++t) {
      short8 bf = *(const short8*)(xs + (t * 16 + col) * DIN + (((s * 4 + q) ^ cx) * 8));
      acc[t] = __builtin_amdgcn_mfma_f32_16x16x32_bf16(af[s], bf, acc[t], 0, 0, 0);
    }
  }

  // D: col=lane&15 -> i; row=q*4+r -> d  (layout verified vs anchor)
  int dq = db * 64 + w * 16 + q * 4;
  float a1v[4], a2v[4];
#pragma unroll
  for (int r = 0; r < 4; ++r) {
    a1v[r] = Ab[dq + r] * LOG2E;
    a2v[r] = Ab[DOUT + dq + r] * LOG2E;
  }
#pragma unroll
  for (int t = 0; t < 4; ++t) {
    floatx4 v = acc[t];
    int icol = i0 + t * 16 + col;  // attention j index
#pragma unroll
    for (int r = 0; r < 4; ++r)
      WhTb[((size_t)(icol >> 5) * DOUT + (dq + r)) * 32 + (icol & 31)] = f2bf_rne(v[r]);
    float p1 = v[0] * a1v[0] + v[1] * a1v[1] + v[2] * a1v[2] + v[3] * a1v[3];
    float p2 = v[0] * a2v[0] + v[1] * a2v[1] + v[2] * a2v[2] + v[3] * a2v[3];
    p1 += __shfl_xor(p1, 16);
    p1 += __shfl_xor(p1, 32);
    p2 += __shfl_xor(p2, 16);
    p2 += __shfl_xor(p2, 32);
    if (q == 0) {
      atomicAdd(&Wh1[icol], p1);
      atomicAdd(&Wh2[icol], p2);
    }
  }
}

// ---------------- fused masked-softmax attention (rank-1 scores) ----------------
// Max-free softmax is exact: |score*log2e| <= ~15, exp2 can't overflow; masked w=0.
// P weights rounded to bf16 (RNE) for MFMA; denominator sums the rounded weights.
// bq: this lane's 8 adjacency bits (mask word pre-shifted by q*8).
__device__ __forceinline__ short8 build_a(unsigned bq, float wh1, floatx4 w2a,
                                          floatx4 w2b, float& lsum) {
  float w2[8] = {w2a[0], w2a[1], w2a[2], w2a[3], w2b[0], w2b[1], w2b[2], w2b[3]};
  float wv[8];
#pragma unroll
  for (int e = 0; e < 8; ++e) {
    float sc = wh1 + w2[e];
    sc = fmaxf(sc, 0.2f * sc);  // LeakyReLU (commutes with the positive log2e scale)
    float ex = __builtin_amdgcn_exp2f(sc);
    wv[e] = ((bq >> e) & 1u) ? ex : 0.0f;
  }
  union { unsigned u[4]; short8 s8; } r;
#pragma unroll
  for (int p = 0; p < 4; ++p) {
    unsigned pk = cvt_pk_bf16(wv[2 * p], wv[2 * p + 1]);
    r.u[p] = pk;
    lsum += __uint_as_float(pk << 16) + __uint_as_float(pk & 0xffff0000u);
  }
  return r.s8;
}

// R6 attn: transaction-bound fix. (a) WhT staging reads the blocked layout —
// per-step tile contiguous, each b128 = 1KB coalesced across the wave (was 64
// lines/instr). (b) adj gather (64 16B segments/instr) replaced by a prologue
// that streams the block's 128x1024 adj strip with coalesced 1KB row-sweeps,
// packs bits via shfl-or tree into LDS masks[128][33]; main loop reads 2
// broadcast ds_read_b32 words/lane/step. Same dbuf + lgkm-only barrier as R3/R5.
__global__ __launch_bounds__(256, 2) void kt_attn(const int* __restrict__ adj,
                                                  const unsigned short* __restrict__ WhTb,
                                                  const float* __restrict__ Wh1,
                                                  const float* __restrict__ Wh2,
                                                  float* __restrict__ accg,
                                                  float* __restrict__ lg) {
  __shared__ __align__(16) unsigned short tileB[2][DOUT * 32];  // 32 KB
  __shared__ unsigned masks[128][33];                           // 16.9 KB (+1 pad: reader bank spread)
  int tid = threadIdx.x;
  int w = tid >> 6, lane = tid & 63;
  int col = lane & 15, q = lane >> 4;
  int s = blockIdx.x & (NSPLIT - 1);  // strip -> XCD: WhT strip stays in that L2
  int ib = blockIdx.x >> 3;
  int i0 = ib * 128;
  int jb = s * STRIP;

  // ---------- phase 1: pack adj strip -> masks[row][jword] ----------
  // wave w packs rows [w*32, w*32+32). Per row: 4 sweeps, each 64 lanes x int4
  // = 1 KB contiguous (coalesced). nibble -> 3-shfl OR tree -> each word
  // written exactly once (no zero-init needed).
#pragma unroll 2
  for (int rr = 0; rr < 32; ++rr) {
    int row = w * 32 + rr;
    const int* rp = adj + (size_t)(i0 + row) * NN + jb;
#pragma unroll
    for (int n = 0; n < 4; ++n) {
      int4 v = *(const int4*)(rp + n * 256 + lane * 4);
      unsigned word = ((unsigned)(v.x & 1) | ((unsigned)(v.y & 1) << 1) |
                       ((unsigned)(v.z & 1) << 2) | ((unsigned)(v.w & 1) << 3))
                      << ((lane & 7) * 4);
      word |= __shfl_xor(word, 1);
      word |= __shfl_xor(word, 2);
      word |= __shfl_xor(word, 4);
      if ((lane & 7) == 0) masks[row][n * 8 + (lane >> 3)] = word;
    }
  }

  // ---------- setup ----------
  int r0 = i0 + w * 32 + col;  // this lane's first score row
  float wh1r0 = Wh1[r0];
  float wh1r1 = Wh1[r0 + 16];
  int qs = q * 8;
  int rl0 = w * 32 + col, rl1 = rl0 + 16;  // local mask rows

  // blocked staging: step-k tile = 16 KB contiguous at (s*32+k)*8192 shorts.
  // thread covers chunks m*256+tid -> global reads coalesced 1KB/instr.
  const unsigned short* gW = WhTb + (size_t)(s * 32) * 8192 + tid * 8;
  // LDS write: chunk m*256+tid = row d=m*64+(tid>>2), logical j-chunk tid&3,
  // physical chunk ^ key, key(d)=(d>>1)&3 = (tid>>3)&3 (m*64 drops out).
  int wswz = ((tid & 3) ^ ((tid >> 3) & 3)) * 8;
  unsigned short* lw0 = &tileB[0][(tid >> 2) * 32 + wswz];
  // reader identical to R5 (measured 0 conflicts): row t*16+col, chunk q^fc
  int fc = (col >> 1) & 3;
  const unsigned short* bb0 = &tileB[0][col * 32 + ((q ^ fc) * 8)];

  const float* wp = Wh2 + jb + qs;

  floatx4 acc0[16], acc1[16];
#pragma unroll
  for (int t = 0; t < 16; ++t) {
    acc0[t] = (floatx4)(0.0f);
    acc1[t] = (floatx4)(0.0f);
  }
  float lp0 = 0.f, lp1 = 0.f;

  // prologue: issue step-0 tile loads (independent of masks) before the barrier
  short8 st[4];
#pragma unroll
  for (int m = 0; m < 4; ++m) st[m] = *(const short8*)(gW + m * 2048);

  // masks visible to all waves; lgkm-only (pack loads all consumed already)
  asm volatile("s_waitcnt lgkmcnt(0)\ns_barrier" ::: "memory");

  unsigned mw0 = masks[rl0][0], mw1 = masks[rl1][0];
  floatx4 w2a = *(const floatx4*)wp;
  floatx4 w2b = *(const floatx4*)(wp + 4);

#pragma unroll 1
  for (int k = 0; k < NSTEP; ++k) {
    int bsel = (k & 1) * (DOUT * 32);
    unsigned short* lw = lw0 + bsel;
#pragma unroll
    for (int m = 0; m < 4; ++m) *(short8*)(lw + m * 2048) = st[m];
    if (k + 1 < NSTEP) {  // issue next stage loads before the barrier wait
      const unsigned short* gs = gW + (size_t)(k + 1) * 8192;
#pragma unroll
      for (int m = 0; m < 4; ++m) st[m] = *(const short8*)(gs + m * 2048);
    }
    // lgkm-only barrier (R3/R5-proven): ds_writes visible, prior ds_reads
    // retired; global prefetches keep flying across it.
    asm volatile("s_waitcnt lgkmcnt(0)\ns_barrier" ::: "memory");
    short8 af0 = build_a(mw0 >> qs, wh1r0, w2a, w2b, lp0);
    short8 af1 = build_a(mw1 >> qs, wh1r1, w2a, w2b, lp1);
    if (k + 1 < NSTEP) {  // prefetch next masks (LDS) + Wh2 under the MFMA phase
      mw0 = masks[rl0][k + 1];
      mw1 = masks[rl1][k + 1];
      const float* wn = wp + (k + 1) * 32;
      w2a = *(const floatx4*)wn;
      w2b = *(const floatx4*)(wn + 4);
    }
#pragma unroll
    for (int h = 0; h < 4; ++h) {
      short8 bf[4];
#pragma unroll
      for (int t = 0; t < 4; ++t) bf[t] = *(const short8*)(bb0 + bsel + (h * 4 + t) * 512);
#pragma unroll
      for (int t = 0; t < 4; ++t) {
        acc0[h * 4 + t] =
            __builtin_amdgcn_mfma_f32_16x16x32_bf16(af0, bf[t], acc0[h * 4 + t], 0, 0, 0);
        acc1[h * 4 + t] =
            __builtin_amdgcn_mfma_f32_16x16x32_bf16(af1, bf[t], acc1[h * 4 + t], 0, 0, 0);
      }
    }
  }

  // l reduction across q groups; rows unique per wave -> every wave adds
  lp0 += __shfl_xor(lp0, 16);
  lp0 += __shfl_xor(lp0, 32);
  lp1 += __shfl_xor(lp1, 16);
  lp1 += __shfl_xor(lp1, 32);
  if (lane < 16) {
    atomicAdd(&lg[i0 + w * 32 + lane], lp0);
    atomicAdd(&lg[i0 + w * 32 + 16 + lane], lp1);
  }
  // fp32 partial merge via coalesced atomics (8 strips per address)
#pragma unroll
  for (int T = 0; T < 16; ++T) {
    floatx4 v0 = acc0[T];
    floatx4 v1 = acc1[T];
    int dcol = T * 16 + col;
    int irow0 = i0 + w * 32 + q * 4;
#pragma unroll
    for (int r = 0; r < 4; ++r) atomicAdd(&accg[(size_t)(irow0 + r) * DOUT + dcol], v0[r]);
#pragma unroll
    for (int r = 0; r < 4; ++r)
      atomicAdd(&accg[(size_t)(irow0 + 16 + r) * DOUT + dcol], v1[r]);
  }
}

// ---------------- normalize + ELU -> fp32 out (float4-vectorized) ----------------
__global__ __launch_bounds__(256) void kt_merge(const float* __restrict__ accg,
                                                const float* __restrict__ lg,
                                                float* __restrict__ out) {
  int g = blockIdx.x * 256 + threadIdx.x;  // one 4-float group
  int i = g >> 6;
  float inv = 1.0f / lg[i];
  float4 v = *(const float4*)(accg + (size_t)g * 4);
  float o[4] = {v.x * inv, v.y * inv, v.z * inv, v.w * inv};
#pragma unroll
  for (int r = 0; r < 4; ++r) o[r] = o[r] > 0.f ? o[r] : (__expf(o[r]) - 1.f);
  *(float4*)(out + (size_t)g * 4) = make_float4(o[0], o[1], o[2], o[3]);
}

extern "C" void kernel_launch(void* const* d_in, const int* in_sizes, int n_in,
                              void* d_out, int out_size, void* d_ws, size_t ws_size,
                              hipStream_t stream) {
  const float* X = (const float*)d_in[0];   // input fp32 [8192][512]
  const int* adj = (const int*)d_in[1];     // int32 [8192][8192]
  const float* Wg = (const float*)d_in[2];  // weight fp32 [512][256]
  const float* Ab = (const float*)d_in[3];  // a fp32 [512]
  float* out = (float*)d_out;               // fp32 [8192][256]

  // workspace: accg | lg | Wh1 | Wh2 | WT | WhTb  (~12.4 MB).
  // Xb (bf16 X, 8 MB) EXACTLY aliases accg (dead after gemm1; memset reclaims).
  // WhTb uses the step-blocked layout [j>>5][d][j&31] (same 4 MB footprint).
  // NOTE: harness re-poisons the full ws (+restores inputs) between iterations
  // (~250us fixed tax in dur_us, visible as 1-GiB fillBuffer in rocprof) —
  // nothing may rely on ws persistence; only kernel time is addressable.
  char* ws = (char*)d_ws;
  float* accg = (float*)ws;                  // 8 MB
  unsigned short* Xb = (unsigned short*)ws;  // alias of accg
  size_t off = (size_t)NN * DOUT * 4;
  float* lg = (float*)(ws + off);
  off += (size_t)NN * 4;
  float* Wh1 = (float*)(ws + off);
  off += (size_t)NN * 4;
  float* Wh2 = (float*)(ws + off);
  off += (size_t)NN * 4;
  unsigned short* WT = (unsigned short*)(ws + off);
  off += (size_t)DOUT * DIN * 2;  // 256 KB
  unsigned short* WhTb = (unsigned short*)(ws + off);
  off += (size_t)DOUT * NN * 2;  // 4 MB

  hipMemsetAsync(Wh1, 0, (size_t)NN * 8, stream);  // Wh1+Wh2 (contiguous)
  kt_cvtx<<<2048, 256, 0, stream>>>(X, Xb);
  kt_transpose<<<128, 256, 0, stream>>>(Wg, WT);
  kt_gemm1<<<512, 256, 0, stream>>>(Xb, WT, Ab, WhTb, Wh1, Wh2);
  hipMemsetAsync(ws, 0, (size_t)NN * DOUT * 4 + (size_t)NN * 4, stream);  // accg+lg
  kt_attn<<<(NN / 128) * NSPLIT, 256, 0, stream>>>(adj, WhTb, Wh1, Wh2, accg, lg);
  kt_merge<<<2048, 256, 0, stream>>>(accg, lg, out);
}

// Round 7
// 455.020 us; speedup vs baseline: 1.1080x; 1.1080x over previous
//
#include <hip/hip_runtime.h>
#include <hip/hip_bf16.h>
#include <stdint.h>

#define NN 8192
#define DIN 512
#define DOUT 256
#define NSPLIT 8
#define STRIP (NN / NSPLIT) /* 1024 */
#define KVBLK 64
#define NSTEP (STRIP / KVBLK) /* 16 */
#define LOG2E 1.4426950408889634f

typedef short short8 __attribute__((ext_vector_type(8)));
typedef float floatx4 __attribute__((ext_vector_type(4)));

__device__ __forceinline__ unsigned short f2bf_rne(float x) {
  unsigned u = __float_as_uint(x);
  u += 0x7fffu + ((u >> 16) & 1u);
  return (unsigned short)(u >> 16);
}

// packed RNE f32->bf16 pair: low16 = bf16(lo), high16 = bf16(hi)
__device__ __forceinline__ unsigned cvt_pk_bf16(float lo, float hi) {
  unsigned r;
  asm("v_cvt_pk_bf16_f32 %0, %1, %2" : "=v"(r) : "v"(lo), "v"(hi));
  return r;
}

// -------- weight transpose+cvt: W fp32 [512][256] -> WT bf16 [256][512] --------
__global__ __launch_bounds__(256) void kt_transpose(const float* __restrict__ Wg,
                                                    unsigned short* __restrict__ WT) {
  __shared__ unsigned short sm[32][33];
  int tid = threadIdx.x;
  int bk = blockIdx.x >> 3;  // k tile
  int bn = blockIdx.x & 7;   // n tile
  int k0 = bk * 32, n0 = bn * 32;
  int r = tid >> 3, c4 = (tid & 7) * 4;
  const float* src = Wg + (size_t)(k0 + r) * DOUT + n0 + c4;
#pragma unroll
  for (int x = 0; x < 4; ++x) sm[r][c4 + x] = f2bf_rne(src[x]);
  __syncthreads();
  unsigned short* dst = WT + (size_t)(n0 + r) * DIN + k0 + c4;
#pragma unroll
  for (int x = 0; x < 4; ++x) dst[x] = sm[c4 + x][r];
}

// -------- X fp32 [8192][512] -> Xb bf16 (aliases accg workspace; accg memset
//          happens AFTER gemm1 consumes Xb) --------
__global__ __launch_bounds__(256) void kt_cvtx(const float* __restrict__ X,
                                               unsigned short* __restrict__ Xb) {
  int g = blockIdx.x * 256 + threadIdx.x;  // one 8-float group per thread
  const float4* p = (const float4*)(X + (size_t)g * 8);
  float4 a = p[0], b = p[1];
  union { unsigned u[4]; short8 s8; } r;
  r.u[0] = cvt_pk_bf16(a.x, a.y);
  r.u[1] = cvt_pk_bf16(a.z, a.w);
  r.u[2] = cvt_pk_bf16(b.x, b.y);
  r.u[3] = cvt_pk_bf16(b.z, b.w);
  *(short8*)(Xb + (size_t)g * 8) = r.s8;
}

// -- GEMM1 (R5-proven, unchanged): LDS-staged X-tile, WhT [d][i] layout. --
__global__ __launch_bounds__(256, 2) void kt_gemm1(const unsigned short* __restrict__ Xb,
                                                   const unsigned short* __restrict__ WT,
                                                   const float* __restrict__ Ab,
                                                   unsigned short* __restrict__ WhT,
                                                   float* __restrict__ Wh1,
                                                   float* __restrict__ Wh2) {
  __shared__ __align__(16) unsigned short xs[64 * DIN];  // 64 KB
  int tid = threadIdx.x;
  int w = tid >> 6, lane = tid & 63;
  int col = lane & 15, q = lane >> 4;
  int ib = blockIdx.x & 127;  // i block (64 each)
  int db = blockIdx.x >> 7;   // d block (64 each)
  int i0 = ib * 64;

  // ---- stage X tile: thread owns row sr = tid>>2, chunks l = (tid&3) + 4n ----
  int sr = tid >> 2, sc = tid & 3, sxor = sr & 7;
  const unsigned short* gX = Xb + (size_t)(i0 + sr) * DIN + sc * 8;
  unsigned short* lX = xs + sr * DIN;
  short8 stg[8];
#pragma unroll
  for (int n = 0; n < 8; ++n) stg[n] = *(const short8*)(gX + n * 32);
#pragma unroll
  for (int n = 0; n < 8; ++n) {
    int l = sc + n * 4;
    *(short8*)(lX + ((l ^ sxor) * 8)) = stg[n];
  }
#pragma unroll
  for (int n = 8; n < 16; ++n) stg[n - 8] = *(const short8*)(gX + n * 32);
#pragma unroll
  for (int n = 8; n < 16; ++n) {
    int l = sc + n * 4;
    *(short8*)(lX + ((l ^ sxor) * 8)) = stg[n - 8];
  }

  // ---- prefetch all 16 A-frags (fly during the barrier drain) ----
  int drow = db * 64 + w * 16 + col;  // A row (d)
  const unsigned short* abase = WT + (size_t)drow * DIN + q * 8;
  short8 af[16];
#pragma unroll
  for (int s = 0; s < 16; ++s) af[s] = *(const short8*)(abase + s * 32);

  __syncthreads();

  floatx4 acc[4];
#pragma unroll
  for (int t = 0; t < 4; ++t) acc[t] = (floatx4)(0.0f);
  int cx = col & 7;  // reader XOR: (t*16+col)&7 == col&7
#pragma unroll
  for (int s = 0; s < 16; ++s) {
#pragma unroll
    for (int t = 0; t < 4; ++t) {
      short8 bf = *(const short8*)(xs + (t * 16 + col) * DIN + (((s * 4 + q) ^ cx) * 8));
      acc[t] = __builtin_amdgcn_mfma_f32_16x16x32_bf16(af[s], bf, acc[t], 0, 0, 0);
    }
  }

  // D: col=lane&15 -> i; row=q*4+r -> d  (layout verified vs anchor)
  int dq = db * 64 + w * 16 + q * 4;
  float a1v[4], a2v[4];
#pragma unroll
  for (int r = 0; r < 4; ++r) {
    a1v[r] = Ab[dq + r] * LOG2E;
    a2v[r] = Ab[DOUT + dq + r] * LOG2E;
  }
#pragma unroll
  for (int t = 0; t < 4; ++t) {
    floatx4 v = acc[t];
    int icol = i0 + t * 16 + col;
#pragma unroll
    for (int r = 0; r < 4; ++r) WhT[(size_t)(dq + r) * NN + icol] = f2bf_rne(v[r]);
    float p1 = v[0] * a1v[0] + v[1] * a1v[1] + v[2] * a1v[2] + v[3] * a1v[3];
    float p2 = v[0] * a2v[0] + v[1] * a2v[1] + v[2] * a2v[2] + v[3] * a2v[3];
    p1 += __shfl_xor(p1, 16);
    p1 += __shfl_xor(p1, 32);
    p2 += __shfl_xor(p2, 16);
    p2 += __shfl_xor(p2, 32);
    if (q == 0) {
      atomicAdd(&Wh1[icol], p1);
      atomicAdd(&Wh2[icol], p2);
    }
  }
}

// ---------------- fused masked-softmax attention (rank-1 scores) ----------------
// Max-free softmax is exact: |score*log2e| <= ~15, exp2 can't overflow; masked w=0.
// P weights rounded to bf16 (RNE) for MFMA; denominator sums the rounded weights.
// Wh1/Wh2 arrive pre-scaled by log2(e).
__device__ __forceinline__ short8 build_a(int4 pa, int4 pb, float wh1, floatx4 w2a,
                                          floatx4 w2b, float& lsum) {
  int av[8] = {pa.x, pa.y, pa.z, pa.w, pb.x, pb.y, pb.z, pb.w};
  float w2[8] = {w2a[0], w2a[1], w2a[2], w2a[3], w2b[0], w2b[1], w2b[2], w2b[3]};
  float wv[8];
#pragma unroll
  for (int e = 0; e < 8; ++e) {
    float sc = wh1 + w2[e];
    sc = fmaxf(sc, 0.2f * sc);  // LeakyReLU (commutes with the positive log2e scale)
    float ex = __builtin_amdgcn_exp2f(sc);
    wv[e] = (av[e] != 0) ? ex : 0.0f;
  }
  union { unsigned u[4]; short8 s8; } r;
#pragma unroll
  for (int p = 0; p < 4; ++p) {
    unsigned pk = cvt_pk_bf16(wv[2 * p], wv[2 * p + 1]);
    r.u[p] = pk;
    lsum += __uint_as_float(pk << 16) + __uint_as_float(pk & 0xffff0000u);
  }
  return r.s8;
}

// R7 attn: KVBLK=64 — half the steps (16), double the work per step. Rationale:
// measured per-block-step time ~3k cyc is INVARIANT when per-step work halves
// (R3 vs R4) -> fixed per-step overhead S (barrier convoy + staging vmcnt +
// adj-latency + af->MFMA chain) dominates; 16x(S+2W) < 32x(S+W). Fatter steps
// also stretch prefetch flight to ~2x HBM loaded latency.
// Tile [256 d][64 j] (128-B rows): chunk-XOR swizzle phys = chunk ^ (d&7) makes
// both staging writes and frag reads land 8 lanes on each of the 8 16-B slots
// per b128 instr = structural optimum. Wh2 lives in LDS (4 KB, broadcast reads)
// to stay under the 256-reg/wave budget (launch_bounds(256,2) pins 2 waves/SIMD).
__global__ __launch_bounds__(256, 2) void kt_attn(const int* __restrict__ adj,
                                                  const unsigned short* __restrict__ WhT,
                                                  const float* __restrict__ Wh1,
                                                  const float* __restrict__ Wh2,
                                                  float* __restrict__ accg,
                                                  float* __restrict__ lg) {
  __shared__ __align__(16) unsigned short tileB[2][DOUT * KVBLK];  // 2 x 32 KB
  __shared__ __align__(16) float wh2s[STRIP];                      // 4 KB
  int tid = threadIdx.x;
  int w = tid >> 6, lane = tid & 63;
  int col = lane & 15, q = lane >> 4;
  int s = blockIdx.x & (NSPLIT - 1);  // strip -> XCD: WhT strip stays in that L2
  int ib = blockIdx.x >> 3;
  int i0 = ib * 128;
  int jb = s * STRIP;

  // Wh2 strip -> LDS once (256 threads x float4 = 1024 floats)
  ((float4*)wh2s)[tid] = ((const float4*)(Wh2 + jb))[tid];

  int r0 = i0 + w * 32 + col;  // this lane's first score row
  float wh1r0 = Wh1[r0];
  float wh1r1 = Wh1[r0 + 16];

  // staging: thread owns WhT row d = tid; 64-j slices, 3-bit chunk XOR swizzle
  int sw = tid & 7;
  const unsigned short* gsrc = WhT + (size_t)tid * NN + jb;
  unsigned short* lrow0 = &tileB[0][tid * KVBLK];

  // reader: row d = t*16+col (d&7 == col&7); logical chunk = h*4+q
  int ck = col & 7;
  int off0 = col * KVBLK + ((q ^ ck) * 8);        // half 0 (chunk q)
  int off1 = col * KVBLK + (((4 + q) ^ ck) * 8);  // half 1 (chunk 4+q)
  const unsigned short* tb0 = &tileB[0][0];

  const int* aptr0 = adj + ((size_t)r0 << 13) + jb + q * 8;
  const int* aptr1 = adj + ((size_t)(r0 + 16) << 13) + jb + q * 8;

  floatx4 acc0[16], acc1[16];
#pragma unroll
  for (int t = 0; t < 16; ++t) {
    acc0[t] = (floatx4)(0.0f);
    acc1[t] = (floatx4)(0.0f);
  }
  float lp0 = 0.f, lp1 = 0.f;

  // prologue prefetch: step-0 tile rows + adj (both 32-j halves)
  short8 st[8];
#pragma unroll
  for (int n = 0; n < 8; ++n) st[n] = *(const short8*)(gsrc + n * 8);
  int4 aA0a = *(const int4*)aptr0;          // h0 row0
  int4 aA0b = *(const int4*)(aptr0 + 4);
  int4 aA1a = *(const int4*)aptr1;          // h0 row1
  int4 aA1b = *(const int4*)(aptr1 + 4);
  int4 aB0a = *(const int4*)(aptr0 + 32);   // h1 row0
  int4 aB0b = *(const int4*)(aptr0 + 36);
  int4 aB1a = *(const int4*)(aptr1 + 32);   // h1 row1
  int4 aB1b = *(const int4*)(aptr1 + 36);

#pragma unroll 1
  for (int k = 0; k < NSTEP; ++k) {
    int bsel = (k & 1) * (DOUT * KVBLK);
    unsigned short* lw = lrow0 + bsel;
#pragma unroll
    for (int n = 0; n < 8; ++n) *(short8*)(lw + ((n ^ sw) * 8)) = st[n];
    if (k + 1 < NSTEP) {  // issue next stage loads before the barrier wait
      const unsigned short* gs = gsrc + (size_t)(k + 1) * KVBLK;
#pragma unroll
      for (int n = 0; n < 8; ++n) st[n] = *(const short8*)(gs + n * 8);
    }
    // lgkm-only barrier (R3/R5-proven): ds_writes visible, prior ds_reads
    // retired; global prefetches keep flying across it. Also covers the
    // prologue wh2s ds_write on the first iteration.
    asm volatile("s_waitcnt lgkmcnt(0)\ns_barrier" ::: "memory");
    int jl = k * KVBLK;
    // ---------------- half 0 (j = jl .. jl+32) ----------------
    {
      floatx4 w2a = *(const floatx4*)&wh2s[jl + q * 8];
      floatx4 w2b = *(const floatx4*)&wh2s[jl + q * 8 + 4];
      short8 af0 = build_a(aA0a, aA0b, wh1r0, w2a, w2b, lp0);
      short8 af1 = build_a(aA1a, aA1b, wh1r1, w2a, w2b, lp1);
      if (k + 1 < NSTEP) {  // reload h0 adj for step k+1 (full step of flight)
        int jn = (k + 1) * KVBLK;
        aA0a = *(const int4*)(aptr0 + jn);
        aA0b = *(const int4*)(aptr0 + jn + 4);
        aA1a = *(const int4*)(aptr1 + jn);
        aA1b = *(const int4*)(aptr1 + jn + 4);
      }
      const unsigned short* br = tb0 + bsel + off0;
#pragma unroll
      for (int h = 0; h < 4; ++h) {
        short8 bf[4];
#pragma unroll
        for (int t = 0; t < 4; ++t) bf[t] = *(const short8*)(br + (h * 4 + t) * 1024);
#pragma unroll
        for (int t = 0; t < 4; ++t) {
          acc0[h * 4 + t] =
              __builtin_amdgcn_mfma_f32_16x16x32_bf16(af0, bf[t], acc0[h * 4 + t], 0, 0, 0);
          acc1[h * 4 + t] =
              __builtin_amdgcn_mfma_f32_16x16x32_bf16(af1, bf[t], acc1[h * 4 + t], 0, 0, 0);
        }
      }
    }
    // ---------------- half 1 (j = jl+32 .. jl+64) ----------------
    {
      floatx4 w2a = *(const floatx4*)&wh2s[jl + 32 + q * 8];
      floatx4 w2b = *(const floatx4*)&wh2s[jl + 32 + q * 8 + 4];
      short8 ag0 = build_a(aB0a, aB0b, wh1r0, w2a, w2b, lp0);
      short8 ag1 = build_a(aB1a, aB1b, wh1r1, w2a, w2b, lp1);
      if (k + 1 < NSTEP) {  // reload h1 adj for step k+1
        int jn = (k + 1) * KVBLK + 32;
        aB0a = *(const int4*)(aptr0 + jn);
        aB0b = *(const int4*)(aptr0 + jn + 4);
        aB1a = *(const int4*)(aptr1 + jn);
        aB1b = *(const int4*)(aptr1 + jn + 4);
      }
      const unsigned short* br = tb0 + bsel + off1;
#pragma unroll
      for (int h = 0; h < 4; ++h) {
        short8 bf[4];
#pragma unroll
        for (int t = 0; t < 4; ++t) bf[t] = *(const short8*)(br + (h * 4 + t) * 1024);
#pragma unroll
        for (int t = 0; t < 4; ++t) {
          acc0[h * 4 + t] =
              __builtin_amdgcn_mfma_f32_16x16x32_bf16(ag0, bf[t], acc0[h * 4 + t], 0, 0, 0);
          acc1[h * 4 + t] =
              __builtin_amdgcn_mfma_f32_16x16x32_bf16(ag1, bf[t], acc1[h * 4 + t], 0, 0, 0);
        }
      }
    }
  }

  // l reduction across q groups; rows unique per wave -> every wave adds
  lp0 += __shfl_xor(lp0, 16);
  lp0 += __shfl_xor(lp0, 32);
  lp1 += __shfl_xor(lp1, 16);
  lp1 += __shfl_xor(lp1, 32);
  if (lane < 16) {
    atomicAdd(&lg[i0 + w * 32 + lane], lp0);
    atomicAdd(&lg[i0 + w * 32 + 16 + lane], lp1);
  }
  // fp32 partial merge via coalesced atomics (8 strips per address)
#pragma unroll
  for (int T = 0; T < 16; ++T) {
    floatx4 v0 = acc0[T];
    floatx4 v1 = acc1[T];
    int dcol = T * 16 + col;
    int irow0 = i0 + w * 32 + q * 4;
#pragma unroll
    for (int r = 0; r < 4; ++r) atomicAdd(&accg[(size_t)(irow0 + r) * DOUT + dcol], v0[r]);
#pragma unroll
    for (int r = 0; r < 4; ++r)
      atomicAdd(&accg[(size_t)(irow0 + 16 + r) * DOUT + dcol], v1[r]);
  }
}

// ---------------- normalize + ELU -> fp32 out (float4-vectorized) ----------------
__global__ __launch_bounds__(256) void kt_merge(const float* __restrict__ accg,
                                                const float* __restrict__ lg,
                                                float* __restrict__ out) {
  int g = blockIdx.x * 256 + threadIdx.x;  // one 4-float group
  int i = g >> 6;
  float inv = 1.0f / lg[i];
  float4 v = *(const float4*)(accg + (size_t)g * 4);
  float o[4] = {v.x * inv, v.y * inv, v.z * inv, v.w * inv};
#pragma unroll
  for (int r = 0; r < 4; ++r) o[r] = o[r] > 0.f ? o[r] : (__expf(o[r]) - 1.f);
  *(float4*)(out + (size_t)g * 4) = make_float4(o[0], o[1], o[2], o[3]);
}

extern "C" void kernel_launch(void* const* d_in, const int* in_sizes, int n_in,
                              void* d_out, int out_size, void* d_ws, size_t ws_size,
                              hipStream_t stream) {
  const float* X = (const float*)d_in[0];   // input fp32 [8192][512]
  const int* adj = (const int*)d_in[1];     // int32 [8192][8192]
  const float* Wg = (const float*)d_in[2];  // weight fp32 [512][256]
  const float* Ab = (const float*)d_in[3];  // a fp32 [512]
  float* out = (float*)d_out;               // fp32 [8192][256]

  // workspace: accg | lg | Wh1 | Wh2 | WT | WhT  (~12.4 MB).
  // Xb (bf16 X, 8 MB) EXACTLY aliases accg (dead after gemm1; memset reclaims).
  // NOTE: harness re-poisons the full ws (+restores inputs) between iterations
  // (~250us fixed tax in dur_us, visible as 1-GiB fillBuffer in rocprof) —
  // nothing may rely on ws persistence; only kernel time is addressable.
  char* ws = (char*)d_ws;
  float* accg = (float*)ws;                  // 8 MB
  unsigned short* Xb = (unsigned short*)ws;  // alias of accg
  size_t off = (size_t)NN * DOUT * 4;
  float* lg = (float*)(ws + off);
  off += (size_t)NN * 4;
  float* Wh1 = (float*)(ws + off);
  off += (size_t)NN * 4;
  float* Wh2 = (float*)(ws + off);
  off += (size_t)NN * 4;
  unsigned short* WT = (unsigned short*)(ws + off);
  off += (size_t)DOUT * DIN * 2;  // 256 KB
  unsigned short* WhT = (unsigned short*)(ws + off);
  off += (size_t)DOUT * NN * 2;  // 4 MB

  hipMemsetAsync(Wh1, 0, (size_t)NN * 8, stream);  // Wh1+Wh2 (contiguous)
  kt_cvtx<<<2048, 256, 0, stream>>>(X, Xb);
  kt_transpose<<<128, 256, 0, stream>>>(Wg, WT);
  kt_gemm1<<<512, 256, 0, stream>>>(Xb, WT, Ab, WhT, Wh1, Wh2);
  hipMemsetAsync(ws, 0, (size_t)NN * DOUT * 4 + (size_t)NN * 4, stream);  // accg+lg
  kt_attn<<<(NN / 128) * NSPLIT, 256, 0, stream>>>(adj, WhT, Wh1, Wh2, accg, lg);
  kt_merge<<<2048, 256, 0, stream>>>(accg, lg, out);
}

// Round 8
// 442.327 us; speedup vs baseline: 1.1398x; 1.0287x over previous
//
#include <hip/hip_runtime.h>
#include <hip/hip_bf16.h>
#include <stdint.h>

#define NN 8192
#define DIN 512
#define DOUT 256
#define NSPLIT 8
#define STRIP (NN / NSPLIT) /* 1024 */
#define KVBLK 64
#define NSTEP (STRIP / KVBLK) /* 16 */
#define LOG2E 1.4426950408889634f

typedef short short8 __attribute__((ext_vector_type(8)));
typedef float floatx4 __attribute__((ext_vector_type(4)));

__device__ __forceinline__ unsigned short f2bf_rne(float x) {
  unsigned u = __float_as_uint(x);
  u += 0x7fffu + ((u >> 16) & 1u);
  return (unsigned short)(u >> 16);
}

// packed RNE f32->bf16 pair: low16 = bf16(lo), high16 = bf16(hi)
__device__ __forceinline__ unsigned cvt_pk_bf16(float lo, float hi) {
  unsigned r;
  asm("v_cvt_pk_bf16_f32 %0, %1, %2" : "=v"(r) : "v"(lo), "v"(hi));
  return r;
}

// -------- weight transpose+cvt: W fp32 [512][256] -> WT bf16 [256][512] --------
__global__ __launch_bounds__(256) void kt_transpose(const float* __restrict__ Wg,
                                                    unsigned short* __restrict__ WT) {
  __shared__ unsigned short sm[32][33];
  int tid = threadIdx.x;
  int bk = blockIdx.x >> 3;  // k tile
  int bn = blockIdx.x & 7;   // n tile
  int k0 = bk * 32, n0 = bn * 32;
  int r = tid >> 3, c4 = (tid & 7) * 4;
  const float* src = Wg + (size_t)(k0 + r) * DOUT + n0 + c4;
#pragma unroll
  for (int x = 0; x < 4; ++x) sm[r][c4 + x] = f2bf_rne(src[x]);
  __syncthreads();
  unsigned short* dst = WT + (size_t)(n0 + r) * DIN + k0 + c4;
#pragma unroll
  for (int x = 0; x < 4; ++x) dst[x] = sm[c4 + x][r];
}

// -------- X fp32 [8192][512] -> Xb bf16 (aliases slab 0; gemm1 consumes Xb
//          before attn overwrites the slabs) --------
__global__ __launch_bounds__(256) void kt_cvtx(const float* __restrict__ X,
                                               unsigned short* __restrict__ Xb) {
  int g = blockIdx.x * 256 + threadIdx.x;  // one 8-float group per thread
  const float4* p = (const float4*)(X + (size_t)g * 8);
  float4 a = p[0], b = p[1];
  union { unsigned u[4]; short8 s8; } r;
  r.u[0] = cvt_pk_bf16(a.x, a.y);
  r.u[1] = cvt_pk_bf16(a.z, a.w);
  r.u[2] = cvt_pk_bf16(b.x, b.y);
  r.u[3] = cvt_pk_bf16(b.z, b.w);
  *(short8*)(Xb + (size_t)g * 8) = r.s8;
}

// -- GEMM1 (R5-proven, unchanged): LDS-staged X-tile, WhT [d][i] layout. --
__global__ __launch_bounds__(256, 2) void kt_gemm1(const unsigned short* __restrict__ Xb,
                                                   const unsigned short* __restrict__ WT,
                                                   const float* __restrict__ Ab,
                                                   unsigned short* __restrict__ WhT,
                                                   float* __restrict__ Wh1,
                                                   float* __restrict__ Wh2) {
  __shared__ __align__(16) unsigned short xs[64 * DIN];  // 64 KB
  int tid = threadIdx.x;
  int w = tid >> 6, lane = tid & 63;
  int col = lane & 15, q = lane >> 4;
  int ib = blockIdx.x & 127;  // i block (64 each)
  int db = blockIdx.x >> 7;   // d block (64 each)
  int i0 = ib * 64;

  // ---- stage X tile: thread owns row sr = tid>>2, chunks l = (tid&3) + 4n ----
  int sr = tid >> 2, sc = tid & 3, sxor = sr & 7;
  const unsigned short* gX = Xb + (size_t)(i0 + sr) * DIN + sc * 8;
  unsigned short* lX = xs + sr * DIN;
  short8 stg[8];
#pragma unroll
  for (int n = 0; n < 8; ++n) stg[n] = *(const short8*)(gX + n * 32);
#pragma unroll
  for (int n = 0; n < 8; ++n) {
    int l = sc + n * 4;
    *(short8*)(lX + ((l ^ sxor) * 8)) = stg[n];
  }
#pragma unroll
  for (int n = 8; n < 16; ++n) stg[n - 8] = *(const short8*)(gX + n * 32);
#pragma unroll
  for (int n = 8; n < 16; ++n) {
    int l = sc + n * 4;
    *(short8*)(lX + ((l ^ sxor) * 8)) = stg[n - 8];
  }

  // ---- prefetch all 16 A-frags (fly during the barrier drain) ----
  int drow = db * 64 + w * 16 + col;  // A row (d)
  const unsigned short* abase = WT + (size_t)drow * DIN + q * 8;
  short8 af[16];
#pragma unroll
  for (int s = 0; s < 16; ++s) af[s] = *(const short8*)(abase + s * 32);

  __syncthreads();

  floatx4 acc[4];
#pragma unroll
  for (int t = 0; t < 4; ++t) acc[t] = (floatx4)(0.0f);
  int cx = col & 7;  // reader XOR: (t*16+col)&7 == col&7
#pragma unroll
  for (int s = 0; s < 16; ++s) {
#pragma unroll
    for (int t = 0; t < 4; ++t) {
      short8 bf = *(const short8*)(xs + (t * 16 + col) * DIN + (((s * 4 + q) ^ cx) * 8));
      acc[t] = __builtin_amdgcn_mfma_f32_16x16x32_bf16(af[s], bf, acc[t], 0, 0, 0);
    }
  }

  // D: col=lane&15 -> i; row=q*4+r -> d  (layout verified vs anchor)
  int dq = db * 64 + w * 16 + q * 4;
  float a1v[4], a2v[4];
#pragma unroll
  for (int r = 0; r < 4; ++r) {
    a1v[r] = Ab[dq + r] * LOG2E;
    a2v[r] = Ab[DOUT + dq + r] * LOG2E;
  }
#pragma unroll
  for (int t = 0; t < 4; ++t) {
    floatx4 v = acc[t];
    int icol = i0 + t * 16 + col;
#pragma unroll
    for (int r = 0; r < 4; ++r) WhT[(size_t)(dq + r) * NN + icol] = f2bf_rne(v[r]);
    float p1 = v[0] * a1v[0] + v[1] * a1v[1] + v[2] * a1v[2] + v[3] * a1v[3];
    float p2 = v[0] * a2v[0] + v[1] * a2v[1] + v[2] * a2v[2] + v[3] * a2v[3];
    p1 += __shfl_xor(p1, 16);
    p1 += __shfl_xor(p1, 32);
    p2 += __shfl_xor(p2, 16);
    p2 += __shfl_xor(p2, 32);
    if (q == 0) {
      atomicAdd(&Wh1[icol], p1);
      atomicAdd(&Wh2[icol], p2);
    }
  }
}

// ---------------- fused masked-softmax attention (rank-1 scores) ----------------
// Max-free softmax is exact: |score*log2e| <= ~15, exp2 can't overflow; masked w=0.
// P weights rounded to bf16 (RNE) for MFMA; denominator sums the rounded weights.
// Wh1/Wh2 arrive pre-scaled by log2(e).
__device__ __forceinline__ short8 build_a(int4 pa, int4 pb, float wh1, floatx4 w2a,
                                          floatx4 w2b, float& lsum) {
  int av[8] = {pa.x, pa.y, pa.z, pa.w, pb.x, pb.y, pb.z, pb.w};
  float w2[8] = {w2a[0], w2a[1], w2a[2], w2a[3], w2b[0], w2b[1], w2b[2], w2b[3]};
  float wv[8];
#pragma unroll
  for (int e = 0; e < 8; ++e) {
    float sc = wh1 + w2[e];
    sc = fmaxf(sc, 0.2f * sc);  // LeakyReLU (commutes with the positive log2e scale)
    float ex = __builtin_amdgcn_exp2f(sc);
    wv[e] = (av[e] != 0) ? ex : 0.0f;
  }
  union { unsigned u[4]; short8 s8; } r;
#pragma unroll
  for (int p = 0; p < 4; ++p) {
    unsigned pk = cvt_pk_bf16(wv[2 * p], wv[2 * p + 1]);
    r.u[p] = pk;
    lsum += __uint_as_float(pk << 16) + __uint_as_float(pk & 0xffff0000u);
  }
  return r.s8;
}

// R8 attn: R7 loop BYTE-IDENTICAL; only the merge changed. Theory under test:
// the structure-invariant ~158us floor is the 16.8M device-scope atomicAdds
// (memory-side RMW serialization; WRITE_SIZE==atomic volume exactly, every
// round). Now each (ib,s) block writes its partial to a PRIVATE slab
// accs[s][8192][256] with plain nontemporal stores (no RMW, no contention);
// lg partials likewise lgp[s][8192]. kt_merge sums 8 slabs + ELU (~72 MB
// coalesced ~= 12-15us). accg/lg memset eliminated (slabs fully overwritten).
__global__ __launch_bounds__(256, 2) void kt_attn(const int* __restrict__ adj,
                                                  const unsigned short* __restrict__ WhT,
                                                  const float* __restrict__ Wh1,
                                                  const float* __restrict__ Wh2,
                                                  float* __restrict__ accs,
                                                  float* __restrict__ lgp) {
  __shared__ __align__(16) unsigned short tileB[2][DOUT * KVBLK];  // 2 x 32 KB
  __shared__ __align__(16) float wh2s[STRIP];                      // 4 KB
  int tid = threadIdx.x;
  int w = tid >> 6, lane = tid & 63;
  int col = lane & 15, q = lane >> 4;
  int s = blockIdx.x & (NSPLIT - 1);  // strip -> XCD: WhT strip stays in that L2
  int ib = blockIdx.x >> 3;
  int i0 = ib * 128;
  int jb = s * STRIP;

  // Wh2 strip -> LDS once (256 threads x float4 = 1024 floats)
  ((float4*)wh2s)[tid] = ((const float4*)(Wh2 + jb))[tid];

  int r0 = i0 + w * 32 + col;  // this lane's first score row
  float wh1r0 = Wh1[r0];
  float wh1r1 = Wh1[r0 + 16];

  // staging: thread owns WhT row d = tid; 64-j slices, 3-bit chunk XOR swizzle
  int sw = tid & 7;
  const unsigned short* gsrc = WhT + (size_t)tid * NN + jb;
  unsigned short* lrow0 = &tileB[0][tid * KVBLK];

  // reader: row d = t*16+col (d&7 == col&7); logical chunk = h*4+q
  int ck = col & 7;
  int off0 = col * KVBLK + ((q ^ ck) * 8);        // half 0 (chunk q)
  int off1 = col * KVBLK + (((4 + q) ^ ck) * 8);  // half 1 (chunk 4+q)
  const unsigned short* tb0 = &tileB[0][0];

  const int* aptr0 = adj + ((size_t)r0 << 13) + jb + q * 8;
  const int* aptr1 = adj + ((size_t)(r0 + 16) << 13) + jb + q * 8;

  floatx4 acc0[16], acc1[16];
#pragma unroll
  for (int t = 0; t < 16; ++t) {
    acc0[t] = (floatx4)(0.0f);
    acc1[t] = (floatx4)(0.0f);
  }
  float lp0 = 0.f, lp1 = 0.f;

  // prologue prefetch: step-0 tile rows + adj (both 32-j halves)
  short8 st[8];
#pragma unroll
  for (int n = 0; n < 8; ++n) st[n] = *(const short8*)(gsrc + n * 8);
  int4 aA0a = *(const int4*)aptr0;          // h0 row0
  int4 aA0b = *(const int4*)(aptr0 + 4);
  int4 aA1a = *(const int4*)aptr1;          // h0 row1
  int4 aA1b = *(const int4*)(aptr1 + 4);
  int4 aB0a = *(const int4*)(aptr0 + 32);   // h1 row0
  int4 aB0b = *(const int4*)(aptr0 + 36);
  int4 aB1a = *(const int4*)(aptr1 + 32);   // h1 row1
  int4 aB1b = *(const int4*)(aptr1 + 36);

#pragma unroll 1
  for (int k = 0; k < NSTEP; ++k) {
    int bsel = (k & 1) * (DOUT * KVBLK);
    unsigned short* lw = lrow0 + bsel;
#pragma unroll
    for (int n = 0; n < 8; ++n) *(short8*)(lw + ((n ^ sw) * 8)) = st[n];
    if (k + 1 < NSTEP) {  // issue next stage loads before the barrier wait
      const unsigned short* gs = gsrc + (size_t)(k + 1) * KVBLK;
#pragma unroll
      for (int n = 0; n < 8; ++n) st[n] = *(const short8*)(gs + n * 8);
    }
    // lgkm-only barrier (R3/R5-proven): ds_writes visible, prior ds_reads
    // retired; global prefetches keep flying across it. Also covers the
    // prologue wh2s ds_write on the first iteration.
    asm volatile("s_waitcnt lgkmcnt(0)\ns_barrier" ::: "memory");
    int jl = k * KVBLK;
    // ---------------- half 0 (j = jl .. jl+32) ----------------
    {
      floatx4 w2a = *(const floatx4*)&wh2s[jl + q * 8];
      floatx4 w2b = *(const floatx4*)&wh2s[jl + q * 8 + 4];
      short8 af0 = build_a(aA0a, aA0b, wh1r0, w2a, w2b, lp0);
      short8 af1 = build_a(aA1a, aA1b, wh1r1, w2a, w2b, lp1);
      if (k + 1 < NSTEP) {  // reload h0 adj for step k+1 (full step of flight)
        int jn = (k + 1) * KVBLK;
        aA0a = *(const int4*)(aptr0 + jn);
        aA0b = *(const int4*)(aptr0 + jn + 4);
        aA1a = *(const int4*)(aptr1 + jn);
        aA1b = *(const int4*)(aptr1 + jn + 4);
      }
      const unsigned short* br = tb0 + bsel + off0;
#pragma unroll
      for (int h = 0; h < 4; ++h) {
        short8 bf[4];
#pragma unroll
        for (int t = 0; t < 4; ++t) bf[t] = *(const short8*)(br + (h * 4 + t) * 1024);
#pragma unroll
        for (int t = 0; t < 4; ++t) {
          acc0[h * 4 + t] =
              __builtin_amdgcn_mfma_f32_16x16x32_bf16(af0, bf[t], acc0[h * 4 + t], 0, 0, 0);
          acc1[h * 4 + t] =
              __builtin_amdgcn_mfma_f32_16x16x32_bf16(af1, bf[t], acc1[h * 4 + t], 0, 0, 0);
        }
      }
    }
    // ---------------- half 1 (j = jl+32 .. jl+64) ----------------
    {
      floatx4 w2a = *(const floatx4*)&wh2s[jl + 32 + q * 8];
      floatx4 w2b = *(const floatx4*)&wh2s[jl + 32 + q * 8 + 4];
      short8 ag0 = build_a(aB0a, aB0b, wh1r0, w2a, w2b, lp0);
      short8 ag1 = build_a(aB1a, aB1b, wh1r1, w2a, w2b, lp1);
      if (k + 1 < NSTEP) {  // reload h1 adj for step k+1
        int jn = (k + 1) * KVBLK + 32;
        aB0a = *(const int4*)(aptr0 + jn);
        aB0b = *(const int4*)(aptr0 + jn + 4);
        aB1a = *(const int4*)(aptr1 + jn);
        aB1b = *(const int4*)(aptr1 + jn + 4);
      }
      const unsigned short* br = tb0 + bsel + off1;
#pragma unroll
      for (int h = 0; h < 4; ++h) {
        short8 bf[4];
#pragma unroll
        for (int t = 0; t < 4; ++t) bf[t] = *(const short8*)(br + (h * 4 + t) * 1024);
#pragma unroll
        for (int t = 0; t < 4; ++t) {
          acc0[h * 4 + t] =
              __builtin_amdgcn_mfma_f32_16x16x32_bf16(ag0, bf[t], acc0[h * 4 + t], 0, 0, 0);
          acc1[h * 4 + t] =
              __builtin_amdgcn_mfma_f32_16x16x32_bf16(ag1, bf[t], acc1[h * 4 + t], 0, 0, 0);
        }
      }
    }
  }

  // l reduction across q groups; rows unique per wave -> exactly one writer per
  // (strip, row): plain nontemporal store to the strip-private partial.
  lp0 += __shfl_xor(lp0, 16);
  lp0 += __shfl_xor(lp0, 32);
  lp1 += __shfl_xor(lp1, 16);
  lp1 += __shfl_xor(lp1, 32);
  if (lane < 16) {
    __builtin_nontemporal_store(lp0, &lgp[(size_t)s * NN + i0 + w * 32 + lane]);
    __builtin_nontemporal_store(lp1, &lgp[(size_t)s * NN + i0 + w * 32 + 16 + lane]);
  }
  // partial O -> strip-private slab, plain nontemporal stores (NO atomics).
  float* slab = accs + (size_t)s * NN * DOUT;
#pragma unroll
  for (int T = 0; T < 16; ++T) {
    floatx4 v0 = acc0[T];
    floatx4 v1 = acc1[T];
    int dcol = T * 16 + col;
    int irow0 = i0 + w * 32 + q * 4;
#pragma unroll
    for (int r = 0; r < 4; ++r)
      __builtin_nontemporal_store(v0[r], &slab[(size_t)(irow0 + r) * DOUT + dcol]);
#pragma unroll
    for (int r = 0; r < 4; ++r)
      __builtin_nontemporal_store(v1[r], &slab[(size_t)(irow0 + 16 + r) * DOUT + dcol]);
  }
}

// ------- merge 8 strip slabs + lg partials, normalize + ELU -> fp32 out -------
__global__ __launch_bounds__(256) void kt_merge(const float* __restrict__ accs,
                                                const float* __restrict__ lgp,
                                                float* __restrict__ out) {
  int g = blockIdx.x * 256 + threadIdx.x;  // one 4-float group; 2048*256*4 = NN*DOUT
  int i = g >> 6;
  float l = 0.f;
#pragma unroll
  for (int s = 0; s < NSPLIT; ++s) l += lgp[(size_t)s * NN + i];
  float4 a = *(const float4*)(accs + (size_t)g * 4);
#pragma unroll
  for (int s = 1; s < NSPLIT; ++s) {
    float4 b = *(const float4*)(accs + (size_t)s * NN * DOUT + (size_t)g * 4);
    a.x += b.x; a.y += b.y; a.z += b.z; a.w += b.w;
  }
  float inv = 1.0f / l;
  float o[4] = {a.x * inv, a.y * inv, a.z * inv, a.w * inv};
#pragma unroll
  for (int r = 0; r < 4; ++r) o[r] = o[r] > 0.f ? o[r] : (__expf(o[r]) - 1.f);
  *(float4*)(out + (size_t)g * 4) = make_float4(o[0], o[1], o[2], o[3]);
}

extern "C" void kernel_launch(void* const* d_in, const int* in_sizes, int n_in,
                              void* d_out, int out_size, void* d_ws, size_t ws_size,
                              hipStream_t stream) {
  const float* X = (const float*)d_in[0];   // input fp32 [8192][512]
  const int* adj = (const int*)d_in[1];     // int32 [8192][8192]
  const float* Wg = (const float*)d_in[2];  // weight fp32 [512][256]
  const float* Ab = (const float*)d_in[3];  // a fp32 [512]
  float* out = (float*)d_out;               // fp32 [8192][256]

  // workspace: accs[8 slabs, 64 MB] | lgp[8][NN] | Wh1 | Wh2 | WT | WhT (~81 MB
  // of the 1-GiB ws). Xb (bf16 X, 8 MB) aliases slab 0 (gemm1 consumes it
  // before attn writes slabs). No accg/lg memset needed: slabs+lgp are fully
  // overwritten by attn every iteration.
  char* ws = (char*)d_ws;
  float* accs = (float*)ws;                  // 8 x 8 MB slabs
  unsigned short* Xb = (unsigned short*)ws;  // alias of slab 0
  size_t off = (size_t)NSPLIT * NN * DOUT * 4;  // 64 MB
  float* lgp = (float*)(ws + off);
  off += (size_t)NSPLIT * NN * 4;  // 256 KB
  float* Wh1 = (float*)(ws + off);
  off += (size_t)NN * 4;
  float* Wh2 = (float*)(ws + off);
  off += (size_t)NN * 4;
  unsigned short* WT = (unsigned short*)(ws + off);
  off += (size_t)DOUT * DIN * 2;  // 256 KB
  unsigned short* WhT = (unsigned short*)(ws + off);
  off += (size_t)DOUT * NN * 2;  // 4 MB

  hipMemsetAsync(Wh1, 0, (size_t)NN * 8, stream);  // Wh1+Wh2 (contiguous)
  kt_cvtx<<<2048, 256, 0, stream>>>(X, Xb);
  kt_transpose<<<128, 256, 0, stream>>>(Wg, WT);
  kt_gemm1<<<512, 256, 0, stream>>>(Xb, WT, Ab, WhT, Wh1, Wh2);
  kt_attn<<<(NN / 128) * NSPLIT, 256, 0, stream>>>(adj, WhT, Wh1, Wh2, accs, lgp);
  kt_merge<<<2048, 256, 0, stream>>>(accs, lgp, out);
}